// Round 11
// baseline (159.617 us; speedup 1.0000x reference)
//
#include <hip/hip_runtime.h>
#include <hip/hip_bf16.h>
#include <math.h>

// Problem constants (from reference)
#define D_BINS 59
#define CTX    80
#define O_TOT  139      // D_BINS + CTX
#define K_CIN  256
#define PIXELS 704      // 16*44
#define BNPAIR 24       // B*N = 4*6
#define BEVHW  16384    // 128*128
#define NBATCH 4
#define NPIX   (BNPAIR * PIXELS)            // 16,896

// Coarse binning: tile = 8 rows x 16 cols of BEV cells -> 128 cells/tile,
// 128 tiles/batch, 512 buckets. ~1947 points/bucket, ~15 points/cell.
#define NTILE   128
#define NBUCKET (NBATCH * NTILE)            // 512
#define TCELLS  128

// Fused blocks: 32 pixels each -> 22 ptiles x 24 bn = 528 blocks.
#define PTILE   32
#define NPT     (PIXELS / PTILE)            // 22
#define NBLK    (NPT * BNPAIR)              // 528
#define EPB     (PTILE * D_BINS)            // 1,888 entries per block region

// Gather LDS list capacity (bucket mean 1947, sd ~44; slow-path covers >CAP).
#define CAP     2816
#define CAPP    (CAP + TCELLS * 7)          // + max pad-to-8 slack

// Workspace layout (4B units):
#define CTX_OFF    0                                    // bf16: NPIX*CTX/2 u32
#define CNTMAT_OFF (CTX_OFF + (NPIX * CTX) / 2)
#define OFSMAT_OFF (CNTMAT_OFF + NBLK * NBUCKET)
#define PLIST_OFF  (OFSMAT_OFF + NBLK * NBUCKET)

// ---------------------------------------------------------------------------
// Kernel 1 (fused): GEMM + softmax + bucket-sort fill, one block per
// (bn, 32-pixel tile). Logits never leave the block (xdepth eliminated).
//  - GEMM: 139x32 tile, 5x4 micro-tile (As stride-5 reads: odd -> conflict-
//    free; Bs b128: 2-way -> free). K-step 16.
//  - softmax: 8 threads/pixel, 8 bins each, LDS 8-way reduce.
//  - fill: bucket codes live in 8 regs/thread; LDS hist+scan; entries
//    placed bucket-sorted into this block's PRIVATE plist region.
// ---------------------------------------------------------------------------
__global__ __launch_bounds__(256) void fused_kernel(
    const float* __restrict__ img,    // (BNPAIR, 256, 704)
    const float* __restrict__ w,      // (139, 256)
    const float* __restrict__ bias,   // (139)
    const int*   __restrict__ geom,   // (pt, 2)
    __hip_bfloat16* __restrict__ ctx, // (bn, 704, 80) bf16
    uint2*       __restrict__ plist,  // [NBLK][EPB]
    int*         __restrict__ cntmat, // [NBLK][NBUCKET]
    int*         __restrict__ ofsmat) // [NBLK][NBUCKET]
{
    __shared__ union {
        struct { float As[16][161]; float Bs[16][32]; } p1;     // 12.3 KB
        struct {
            float L[D_BINS][PTILE + 1];          // 59x33 logits
            float red[8][PTILE];                 // softmax reduce
            int lh[NBUCKET], lofs[NBUCKET], lcur[NBUCKET];
            int s[256];
        } p2;                                                   // ~15.8 KB
    } sm;

    const int tid = threadIdx.x;
    const int pt  = blockIdx.x;        // 0..21
    const int bn  = blockIdx.y;        // 0..23
    const int p0  = pt * PTILE;
    const int blk = bn * NPT + pt;     // fill-block id 0..527
    const int b   = bn / 6;

    // ---------------- GEMM phase ----------------
    const int tx = tid & 7;            // pixel group: px tx*4..tx*4+3
    const int ty = tid >> 3;           // output group: o ty*5..ty*5+4
    const float* imgbn = img + (size_t)bn * K_CIN * PIXELS;

    float acc[5][4];
#pragma unroll
    for (int i = 0; i < 5; ++i)
#pragma unroll
        for (int j = 0; j < 4; ++j) acc[i][j] = 0.f;

    for (int kt = 0; kt < K_CIN; kt += 16) {
        // A staging: 139 o x 16 k, float4 (k-contiguous) per element-group
        for (int e = tid; e < O_TOT * 4; e += 256) {
            const int o  = e >> 2;
            const int kc = (e & 3) * 4;
            const float4 v = *(const float4*)&w[(size_t)o * K_CIN + kt + kc];
            sm.p1.As[kc + 0][o] = v.x;
            sm.p1.As[kc + 1][o] = v.y;
            sm.p1.As[kc + 2][o] = v.z;
            sm.p1.As[kc + 3][o] = v.w;
        }
        // B staging: 16 k x 32 p (128 threads, one float4 each)
        if (tid < 128) {
            const int kl = tid >> 3;
            const int p4 = (tid & 7) * 4;
            *(float4*)&sm.p1.Bs[kl][p4] =
                *(const float4*)&imgbn[(size_t)(kt + kl) * PIXELS + p0 + p4];
        }
        __syncthreads();

#pragma unroll
        for (int kk = 0; kk < 16; ++kk) {
            const float4 b4 = *(const float4*)&sm.p1.Bs[kk][tx * 4];
            const float bv4[4] = {b4.x, b4.y, b4.z, b4.w};
            float av[5];
#pragma unroll
            for (int i = 0; i < 5; ++i) av[i] = sm.p1.As[kk][ty * 5 + i];
#pragma unroll
            for (int i = 0; i < 5; ++i)
#pragma unroll
                for (int j = 0; j < 4; ++j)
                    acc[i][j] += av[i] * bv4[j];
        }
        __syncthreads();
    }

    // ---------------- epilogue: logits -> LDS, context -> global bf16 ------
#pragma unroll
    for (int i = 0; i < 5; ++i) {
        const int o = ty * 5 + i;
        if (o >= O_TOT) continue;
        const float bv = bias[o];
        if (o < D_BINS) {
#pragma unroll
            for (int j = 0; j < 4; ++j)
                sm.p2.L[o][tx * 4 + j] = acc[i][j] + bv;
        } else {
            const int c = o - D_BINS;
            __hip_bfloat16* dst = ctx + ((size_t)bn * PIXELS + p0 + tx * 4) * CTX + c;
#pragma unroll
            for (int j = 0; j < 4; ++j)
                dst[(size_t)j * CTX] = __float2bfloat16(acc[i][j] + bv);
        }
    }
    sm.p2.lh[tid] = 0;
    sm.p2.lh[tid + 256] = 0;
    __syncthreads();

    // ---------------- softmax: 8 threads/pixel, 8 bins each ----------------
    const int px = tid & (PTILE - 1);
    const int h  = tid >> 5;                    // 0..7
    const int d0 = h * 8;                       // bins d0..d0+7 (d<59 guard)
    float v[8];
    float lm = -INFINITY;
#pragma unroll
    for (int i = 0; i < 8; ++i) {
        const int d = d0 + i;
        v[i] = (d < D_BINS) ? sm.p2.L[d][px] : -INFINITY;
        lm = fmaxf(lm, v[i]);
    }
    sm.p2.red[h][px] = lm;
    __syncthreads();
    float gm = sm.p2.red[0][px];
#pragma unroll
    for (int hh = 1; hh < 8; ++hh) gm = fmaxf(gm, sm.p2.red[hh][px]);
    __syncthreads();
    float ls = 0.f;
#pragma unroll
    for (int i = 0; i < 8; ++i) {
        v[i] = __expf(v[i] - gm);               // -inf -> 0 for pad bins
        ls += v[i];
    }
    sm.p2.red[h][px] = ls;
    __syncthreads();
    float tot = 0.f;
#pragma unroll
    for (int hh = 0; hh < 8; ++hh) tot += sm.p2.red[hh][px];
    const float inv = 1.f / tot;
#pragma unroll
    for (int i = 0; i < 8; ++i) v[i] *= inv;

    // ---------------- fill: geom -> bucket codes (regs) + LDS hist ---------
    const int pp = p0 + px;
    const int2* g2 = (const int2*)geom;
    unsigned uu[8];
#pragma unroll
    for (int i = 0; i < 8; ++i) {
        const int d = d0 + i;
        if (d < D_BINS) {
            const int2 g = g2[((size_t)(bn * D_BINS + d)) * PIXELS + pp];
            const int bucket = b * NTILE + (g.x >> 3) * 8 + (g.y >> 4);
            const int cell   = (g.x & 7) * 16 + (g.y & 15);
            uu[i] = (unsigned)((bucket << 7) | cell);
            atomicAdd(&sm.p2.lh[bucket], 1);
        }
    }
    __syncthreads();

    // exclusive scan over 512 buckets with 256 threads (pairwise)
    const int v0 = sm.p2.lh[2 * tid];
    const int v1 = sm.p2.lh[2 * tid + 1];
    const int pr = v0 + v1;
    sm.p2.s[tid] = pr;
    __syncthreads();
#pragma unroll
    for (int off = 1; off < 256; off <<= 1) {
        int t = (tid >= off) ? sm.p2.s[tid - off] : 0;
        __syncthreads();
        sm.p2.s[tid] += t;
        __syncthreads();
    }
    const int excl = sm.p2.s[tid] - pr;
    sm.p2.lofs[2 * tid]     = excl;
    sm.p2.lofs[2 * tid + 1] = excl + v0;
    sm.p2.lcur[2 * tid]     = 0;
    sm.p2.lcur[2 * tid + 1] = 0;
    cntmat[(size_t)blk * NBUCKET + 2 * tid]     = v0;
    cntmat[(size_t)blk * NBUCKET + 2 * tid + 1] = v1;
    ofsmat[(size_t)blk * NBUCKET + 2 * tid]     = excl;
    ofsmat[(size_t)blk * NBUCKET + 2 * tid + 1] = excl + v0;
    __syncthreads();

    // place entries bucket-sorted into this block's private region
    uint2* dst = plist + (size_t)blk * EPB;
    const unsigned ctxoff = (unsigned)((bn * PIXELS + pp) * CTX);
#pragma unroll
    for (int i = 0; i < 8; ++i) {
        const int d = d0 + i;
        if (d < D_BINS) {
            const int bkt = (int)(uu[i] >> 7);
            const int pos = sm.p2.lofs[bkt] + atomicAdd(&sm.p2.lcur[bkt], 1);
            dst[pos] = make_uint2(__float_as_uint(v[i]),
                                  (ctxoff << 7) | (uu[i] & 127u));
        }
    }
}

// ---------------------------------------------------------------------------
// Kernel 2 (gather): one block per bucket (1024 thr = 16 waves).
// 528 small segments copied by 4-lane groups; segment scan (1024-wide)
// overlays bufB's LDS. Then: cell-sort into bufB (pad-to-8); lane l<40 owns
// channel pair (2l,2l+1), one u32 (2xbf16) load per point, 8-pt unroll;
// LDS-staged full-64B-line epilogue to (B,C,H,W).
// ---------------------------------------------------------------------------
__global__ __launch_bounds__(1024) void gather_kernel(
    const uint2* __restrict__ plist,
    const int*   __restrict__ cntmat,
    const int*   __restrict__ ofsmat,
    const unsigned short* __restrict__ ctx,   // bf16 bits, (bn,pix,80)
    float*       __restrict__ out)
{
    __shared__ float sacc[CTX][TCELLS + 1];   // 41.3 KB
    __shared__ uint2 bufB[CAPP];              // 29.7 KB (sg overlays this)
    __shared__ int segcnt[NBLK], segofs[NBLK];
    __shared__ int cellcnt[TCELLS], celloff[TCELLS], cellcur[TCELLS], sc[TCELLS];
    uint2* bufA = (uint2*)sacc;               // bufA dead once sacc live
    int*   sg   = (int*)bufB;                 // sg dead before bufB written

    const int tid    = threadIdx.x;
    const int wv     = tid >> 6;
    const int lane   = tid & 63;
    const int bucket = blockIdx.x;

    // 1024-wide scan of the 528 segment counts
    {
        const int c = (tid < NBLK) ? cntmat[(size_t)tid * NBUCKET + bucket] : 0;
        sg[tid] = c;
        if (tid < NBLK) segcnt[tid] = c;
    }
    __syncthreads();
#pragma unroll
    for (int off = 1; off < 1024; off <<= 1) {
        int t = (tid >= off) ? sg[tid - off] : 0;
        __syncthreads();
        sg[tid] += t;
        __syncthreads();
    }
    if (tid < NBLK) segofs[tid] = sg[tid] - segcnt[tid];
    const int total = sg[1023];
    __syncthreads();

    // copy segments -> bufA; 4-lane groups (avg segment ~3.7 entries)
    {
        const int grp = lane >> 2;            // 0..15
        const int sub = lane & 3;
        for (int s = wv * 16 + grp; s < NBLK; s += 256) {
            const int n = segcnt[s];
            if (!n) continue;
            const int dstb = segofs[s];
            const uint2* sp = plist + (size_t)s * EPB
                            + ofsmat[(size_t)s * NBUCKET + bucket];
            for (int i = sub; i < n; i += 4) {
                const int d = dstb + i;
                if (d < CAP) bufA[d] = sp[i];
            }
        }
    }
    const int ncap = (total < CAP) ? total : CAP;
    __syncthreads();

    // cell histogram
    if (tid < TCELLS) cellcnt[tid] = 0;
    __syncthreads();
    for (int i = tid; i < ncap; i += 1024)
        atomicAdd(&cellcnt[bufA[i].y & 127u], 1);
    __syncthreads();
    // scan over PADDED counts (round up to 8)
    if (tid < TCELLS) sc[tid] = (cellcnt[tid] + 7) & ~7;
    __syncthreads();
#pragma unroll
    for (int off = 1; off < TCELLS; off <<= 1) {
        int t = (tid < TCELLS && tid >= off) ? sc[tid - off] : 0;
        __syncthreads();
        if (tid < TCELLS) sc[tid] += t;
        __syncthreads();
    }
    if (tid < TCELLS) {
        celloff[tid] = sc[tid] - ((cellcnt[tid] + 7) & ~7);
        cellcur[tid] = 0;
    }
    __syncthreads();
    const int padtotal = sc[TCELLS - 1];
    // zero pad region (pads: depth=0 -> contribute 0; ctxoff=0 harmless)
    for (int i = tid; i < padtotal; i += 1024) bufB[i] = make_uint2(0u, 0u);
    __syncthreads();
    // reorder bufA -> bufB (cell-sorted, padded)
    for (int i = tid; i < ncap; i += 1024) {
        const uint2 e = bufA[i];
        const int c = (int)(e.y & 127u);
        bufB[celloff[c] + atomicAdd(&cellcur[c], 1)] = e;
    }
    __syncthreads();   // bufA dead; sacc live from here

    // accumulate: wave wv owns cells c = wv, wv+16, ...; lane l<40 owns
    // channels (2l, 2l+1); 8-pt unrolled, one u32 (2xbf16) load per point.
    for (int c = wv; c < TCELLS; c += 16) {
        const int s0 = celloff[c];
        const int pc = (cellcnt[c] + 7) & ~7;
        float a0 = 0.f, a1 = 0.f;
        for (int i = 0; i < pc; i += 8) {
            uint2 e[8];
#pragma unroll
            for (int r = 0; r < 8; ++r) e[r] = bufB[s0 + i + r];   // broadcast
            if (lane < 40) {
                unsigned u[8];
#pragma unroll
                for (int r = 0; r < 8; ++r)
                    u[r] = *(const unsigned*)(ctx + (e[r].y >> 7) + 2 * lane);
#pragma unroll
                for (int r = 0; r < 8; ++r) {
                    const float d  = __uint_as_float(e[r].x);
                    a0 += d * __uint_as_float(u[r] << 16);
                    a1 += d * __uint_as_float(u[r] & 0xffff0000u);
                }
            }
        }
        if (lane < 40) {
            sacc[2 * lane][c]     = a0;
            sacc[2 * lane + 1][c] = a1;
        }
    }

    // slow path for bucket overflow (~20 sigma; correctness only)
    if (total > CAP) {
        for (int blk = 0; blk < NBLK; ++blk) {
            const int dstb = segofs[blk];
            const int n    = segcnt[blk];
            if (dstb + n <= CAP) continue;
            const uint2* sp = plist + (size_t)blk * EPB
                            + ofsmat[(size_t)blk * NBUCKET + bucket];
            const int i0 = (CAP > dstb) ? (CAP - dstb) : 0;
            for (int i = i0; i < n; ++i) {
                const uint2 e = sp[i];
                const int c = (int)(e.y & 127u);
                if ((c & 15) == wv && lane < 40) {
                    const unsigned u = *(const unsigned*)(ctx + (e.y >> 7) + 2 * lane);
                    const float dep = __uint_as_float(e.x);
                    sacc[2 * lane][c]     += dep * __uint_as_float(u << 16);
                    sacc[2 * lane + 1][c] += dep * __uint_as_float(u & 0xffff0000u);
                }
            }
        }
    }
    __syncthreads();

    // epilogue: full 64B line writes to (B,C,H,W)
    const int b  = bucket >> 7;
    const int tl = bucket & 127;
    const int tr = tl >> 3;
    const int tc = tl & 7;
    const int c0  = tid >> 4;
    const int col = tid & 15;
#pragma unroll
    for (int cc = c0; cc < CTX; cc += 64) {
#pragma unroll
        for (int r = 0; r < 8; ++r) {
            out[((size_t)(b * CTX + cc)) * BEVHW + (tr * 8 + r) * 128 + tc * 16 + col]
                = sacc[cc][r * 16 + col];
        }
    }
}

extern "C" void kernel_launch(void* const* d_in, const int* in_sizes, int n_in,
                              void* d_out, int out_size, void* d_ws, size_t ws_size,
                              hipStream_t stream)
{
    const float* img  = (const float*)d_in[0];
    const float* w    = (const float*)d_in[4];
    const float* bias = (const float*)d_in[5];
    const int*   geom = (const int*)d_in[6];
    float*       out  = (float*)d_out;

    float* ws     = (float*)d_ws;
    __hip_bfloat16* ctx = (__hip_bfloat16*)(ws + CTX_OFF);
    int*   cntmat = (int*)(ws + CNTMAT_OFF);
    int*   ofsmat = (int*)(ws + OFSMAT_OFF);
    uint2* plist  = (uint2*)(ws + PLIST_OFF);

    // 1. fused GEMM + softmax + bucket-sort fill (xdepth eliminated)
    {
        dim3 grid(NPT, BNPAIR);   // 22 x 24 = 528 blocks
        fused_kernel<<<grid, 256, 0, stream>>>(img, w, bias, geom,
                                               ctx, plist, cntmat, ofsmat);
    }
    // 2. fused cell-sort + gather per bucket, coalesced (B,C,H,W) writes
    gather_kernel<<<NBUCKET, 1024, 0, stream>>>(plist, cntmat, ofsmat,
                                                (const unsigned short*)ctx, out);
}

// Round 12
// 156.800 us; speedup vs baseline: 1.0180x; 1.0180x over previous
//
#include <hip/hip_runtime.h>
#include <hip/hip_bf16.h>
#include <math.h>

// Problem constants (from reference)
#define D_BINS 59
#define CTX    80
#define O_TOT  139      // D_BINS + CTX
#define K_CIN  256
#define PIXELS 704      // 16*44
#define BNPAIR 24       // B*N = 4*6
#define BEVHW  16384    // 128*128
#define NBATCH 4
#define NPOINT (BNPAIR * D_BINS * PIXELS)   // 996,864
#define NPIX   (BNPAIR * PIXELS)            // 16,896

// Coarse binning: tile = 8 rows x 16 cols of BEV cells -> 128 cells/tile,
// 128 tiles/batch, 512 buckets. ~1947 points/bucket, ~15 points/cell.
#define NTILE   128
#define NBUCKET (NBATCH * NTILE)            // 512
#define TCELLS  128

// Fill blocks: 128 pixels each -> 132 blocks, 2 threads/pixel (30 bins each).
#define PIXB    128
#define NBLK    (NPIX / PIXB)               // 132
#define EPB     (PIXB * D_BINS)             // 7,552 entries per block region

// Gather LDS list capacity (bucket mean 1947, sd ~44; slow-path covers >CAP).
#define CAP     2816
#define CAPP    (CAP + TCELLS * 7)          // + max pad-to-8 slack

// Workspace layout (4B units):
#define XDEPTH_OFF 0
#define CTX_OFF    (XDEPTH_OFF + NPOINT)    // ctx bf16: uses half the region
#define CNTMAT_OFF (CTX_OFF + BNPAIR * PIXELS * CTX)
#define OFSMAT_OFF (CNTMAT_OFF + NBLK * NBUCKET)
#define PLIST_OFF  (OFSMAT_OFF + NBLK * NBUCKET)

// ---------------------------------------------------------------------------
// Kernel 1: per-(b,n) GEMM — R7/R9 structure; ctx epilogue stores BF16 (RNE).
// 64x64 tile, 4x4 micro-tile, K-step 16, conflict-free LDS reads.
// ---------------------------------------------------------------------------
__global__ __launch_bounds__(256) void gemm_kernel(
    const float* __restrict__ img,    // (BNPAIR, 256, 704)
    const float* __restrict__ w,      // (139, 256)
    const float* __restrict__ bias,   // (139)
    float* __restrict__ xdepth,       // (bn, 59, 704) depth LOGITS (fp32)
    __hip_bfloat16* __restrict__ ctx) // (bn, 704, 80) context, BF16
{
    __shared__ float As[16][64];    // [k][o_local]
    __shared__ float Bs[16][64];    // [k][p_local]

    const int tid = threadIdx.x;
    const int tx  = tid & 15;
    const int ty  = tid >> 4;
    const int bn  = blockIdx.z;
    const int o0  = blockIdx.y * 64;
    const int p0  = blockIdx.x * 64;

    const float* imgbn = img + (size_t)bn * K_CIN * PIXELS;

    float acc[4][4];
#pragma unroll
    for (int i = 0; i < 4; ++i)
#pragma unroll
        for (int j = 0; j < 4; ++j) acc[i][j] = 0.f;

    const int a_ol = tid >> 2;          // 0..63
    const int a_kc = (tid & 3) * 4;     // 0,4,8,12
    const int b_kl = tid >> 4;          // 0..15
    const int b_p4 = (tid & 15) * 4;    // 0..60

    for (int kt = 0; kt < K_CIN; kt += 16) {
        {
            const int o = o0 + a_ol;
            float4 v = make_float4(0.f, 0.f, 0.f, 0.f);
            if (o < O_TOT) v = *(const float4*)&w[(size_t)o * K_CIN + kt + a_kc];
            As[a_kc + 0][a_ol] = v.x;
            As[a_kc + 1][a_ol] = v.y;
            As[a_kc + 2][a_ol] = v.z;
            As[a_kc + 3][a_ol] = v.w;
        }
        *(float4*)&Bs[b_kl][b_p4] =
            *(const float4*)&imgbn[(size_t)(kt + b_kl) * PIXELS + p0 + b_p4];
        __syncthreads();

#pragma unroll
        for (int kk = 0; kk < 16; ++kk) {
            const float4 a = *(const float4*)&As[kk][ty * 4];
            const float4 b = *(const float4*)&Bs[kk][tx * 4];
            const float av[4] = {a.x, a.y, a.z, a.w};
            const float bv[4] = {b.x, b.y, b.z, b.w};
#pragma unroll
            for (int i = 0; i < 4; ++i)
#pragma unroll
                for (int j = 0; j < 4; ++j)
                    acc[i][j] += av[i] * bv[j];
        }
        __syncthreads();
    }

#pragma unroll
    for (int i = 0; i < 4; ++i) {
        const int o = o0 + ty * 4 + i;
        if (o >= O_TOT) continue;
        const float bv = bias[o];
        if (o < D_BINS) {
            float4 r = make_float4(acc[i][0] + bv, acc[i][1] + bv,
                                   acc[i][2] + bv, acc[i][3] + bv);
            *(float4*)&xdepth[((size_t)bn * D_BINS + o) * PIXELS + p0 + tx * 4] = r;
        } else {
            const int c = o - D_BINS;
            __hip_bfloat16* dst = ctx + ((size_t)bn * PIXELS + p0 + tx * 4) * CTX + c;
#pragma unroll
            for (int j = 0; j < 4; ++j)
                dst[(size_t)j * CTX] = __float2bfloat16(acc[i][j] + bv);
        }
    }
}

// ---------------------------------------------------------------------------
// Kernel 2 (fill): softmax + binning, fused, zero global atomics.
// 128 pixels/block (132 blocks), 2 threads/pixel (bins h*30..h*30+29).
// ---------------------------------------------------------------------------
__global__ __launch_bounds__(256) void fill_kernel(
    const float* __restrict__ xdepth,   // logits (bn, 59, 704)
    const int*   __restrict__ geom,     // (pt, 2)
    uint2*       __restrict__ plist,    // [NBLK][EPB]
    int*         __restrict__ cntmat,   // [NBLK][NBUCKET]
    int*         __restrict__ ofsmat)   // [NBLK][NBUCKET]
{
    __shared__ unsigned short cache[D_BINS][PIXB];  // 14.75 KB
    __shared__ float red[2][PIXB];
    __shared__ int lh[NBUCKET];
    __shared__ int lofs[NBUCKET];
    __shared__ int lcur[NBUCKET];
    __shared__ int s[256];

    const int tid = threadIdx.x;
    const int px  = tid & (PIXB - 1);
    const int h   = tid >> 7;                   // 0 or 1
    const int pix = blockIdx.x * PIXB + px;     // < NPIX exactly
    const int bn  = pix / PIXELS;
    const int pp  = pix - bn * PIXELS;
    const int b   = bn / 6;
    const int d0  = h * 30;                     // bins d0..d0+29 (d<59 guard)

    if (tid < NBUCKET) { lh[tid] = 0; lh[tid + 256] = 0; }
    __syncthreads();

    const float* base = xdepth + (size_t)bn * D_BINS * PIXELS + pp;
    float v[30];
    float lm = -INFINITY;
#pragma unroll
    for (int i = 0; i < 30; ++i) {
        const int d = d0 + i;
        v[i] = (d < D_BINS) ? base[(size_t)d * PIXELS] : -INFINITY;
        lm = fmaxf(lm, v[i]);
    }
    red[h][px] = lm;
    __syncthreads();
    const float gm = fmaxf(red[0][px], red[1][px]);
    __syncthreads();
    float ls = 0.f;
#pragma unroll
    for (int i = 0; i < 30; ++i) {
        v[i] = __expf(v[i] - gm);
        ls += v[i];
    }
    red[h][px] = ls;
    __syncthreads();
    const float inv = 1.f / (red[0][px] + red[1][px]);
#pragma unroll
    for (int i = 0; i < 30; ++i) v[i] *= inv;

    const int2* g2 = (const int2*)geom;
#pragma unroll
    for (int i = 0; i < 30; ++i) {
        const int d = d0 + i;
        if (d < D_BINS) {
            const int2 g = g2[((size_t)(bn * D_BINS + d)) * PIXELS + pp];
            const int bucket = b * NTILE + (g.x >> 3) * 8 + (g.y >> 4);
            const int cell   = (g.x & 7) * 16 + (g.y & 15);
            cache[d][px] = (unsigned short)((bucket << 7) | cell);
            atomicAdd(&lh[bucket], 1);
        }
    }
    __syncthreads();

    const int v0 = lh[2 * tid];
    const int v1 = lh[2 * tid + 1];
    const int p  = v0 + v1;
    s[tid] = p;
    __syncthreads();
#pragma unroll
    for (int off = 1; off < 256; off <<= 1) {
        int t = (tid >= off) ? s[tid - off] : 0;
        __syncthreads();
        s[tid] += t;
        __syncthreads();
    }
    const int excl = s[tid] - p;
    lofs[2 * tid]     = excl;
    lofs[2 * tid + 1] = excl + v0;
    lcur[2 * tid]     = 0;
    lcur[2 * tid + 1] = 0;
    cntmat[(size_t)blockIdx.x * NBUCKET + 2 * tid]     = v0;
    cntmat[(size_t)blockIdx.x * NBUCKET + 2 * tid + 1] = v1;
    ofsmat[(size_t)blockIdx.x * NBUCKET + 2 * tid]     = excl;
    ofsmat[(size_t)blockIdx.x * NBUCKET + 2 * tid + 1] = excl + v0;
    __syncthreads();

    uint2* dst = plist + (size_t)blockIdx.x * EPB;
    const unsigned ctxoff = (unsigned)((bn * PIXELS + pp) * CTX);
#pragma unroll
    for (int i = 0; i < 30; ++i) {
        const int d = d0 + i;
        if (d < D_BINS) {
            const unsigned u = cache[d][px];
            const int bucket = (int)(u >> 7);
            const int pos = lofs[bucket] + atomicAdd(&lcur[bucket], 1);
            dst[pos] = make_uint2(__float_as_uint(v[i]), (ctxoff << 7) | (u & 127u));
        }
    }
}

// ---------------------------------------------------------------------------
// Kernel 3 (gather): one block per bucket. Segments -> bufA -> cell-sort
// into bufB (pad-to-8). Accumulate: lane l<40 owns channel pair (2l,2l+1),
// ONE u32 (=2xbf16) load per point, unpacked by shift (exact). No pointer
// arrays -> live regs ~32, loads stay 8-deep in flight (R8's VGPR lesson).
// ---------------------------------------------------------------------------
__global__ __launch_bounds__(1024) void gather_kernel(
    const uint2* __restrict__ plist,
    const int*   __restrict__ cntmat,
    const int*   __restrict__ ofsmat,
    const unsigned short* __restrict__ ctx,   // bf16 bits, (bn,pix,80)
    float*       __restrict__ out)
{
    __shared__ float sacc[CTX][TCELLS + 1];   // 41.3 KB
    __shared__ uint2 bufB[CAPP];              // 29 KB
    __shared__ int sg[256];
    __shared__ int segcnt[NBLK], segofs[NBLK];
    __shared__ int cellcnt[TCELLS], celloff[TCELLS], cellcur[TCELLS], sc[TCELLS];
    uint2* bufA = (uint2*)sacc;               // overlay: bufA dead once sacc live

    const int tid    = threadIdx.x;
    const int wv     = tid >> 6;
    const int lane   = tid & 63;
    const int bucket = blockIdx.x;

    // parallel scan of the 132 segment counts (padded to 256)
    if (tid < 256) {
        const int c = (tid < NBLK) ? cntmat[(size_t)tid * NBUCKET + bucket] : 0;
        sg[tid] = c;
        if (tid < NBLK) segcnt[tid] = c;
    }
    __syncthreads();
#pragma unroll
    for (int off = 1; off < 256; off <<= 1) {
        int t = (tid < 256 && tid >= off) ? sg[tid - off] : 0;
        __syncthreads();
        if (tid < 256) sg[tid] += t;
        __syncthreads();
    }
    if (tid < NBLK) segofs[tid] = sg[tid] - segcnt[tid];
    __syncthreads();
    const int total = sg[255];

    for (int blk = wv; blk < NBLK; blk += 16) {
        const int n = segcnt[blk];
        if (!n) continue;
        const int dstb = segofs[blk];
        const uint2* sp = plist + (size_t)blk * EPB + ofsmat[(size_t)blk * NBUCKET + bucket];
        for (int i = lane; i < n; i += 64) {
            const int d = dstb + i;
            if (d < CAP) bufA[d] = sp[i];
        }
    }
    const int ncap = (total < CAP) ? total : CAP;
    __syncthreads();

    // cell histogram
    if (tid < TCELLS) cellcnt[tid] = 0;
    __syncthreads();
    for (int i = tid; i < ncap; i += 1024)
        atomicAdd(&cellcnt[bufA[i].y & 127u], 1);
    __syncthreads();
    // scan over PADDED counts (round up to 8)
    if (tid < TCELLS) sc[tid] = (cellcnt[tid] + 7) & ~7;
    __syncthreads();
#pragma unroll
    for (int off = 1; off < TCELLS; off <<= 1) {
        int t = (tid < TCELLS && tid >= off) ? sc[tid - off] : 0;
        __syncthreads();
        if (tid < TCELLS) sc[tid] += t;
        __syncthreads();
    }
    if (tid < TCELLS) {
        celloff[tid] = sc[tid] - ((cellcnt[tid] + 7) & ~7);
        cellcur[tid] = 0;
    }
    __syncthreads();
    const int padtotal = sc[TCELLS - 1];
    // zero pad region (pads: depth=0 -> contribute 0; ctxoff=0 harmless)
    for (int i = tid; i < padtotal; i += 1024) bufB[i] = make_uint2(0u, 0u);
    __syncthreads();
    // reorder bufA -> bufB (cell-sorted, padded)
    for (int i = tid; i < ncap; i += 1024) {
        const uint2 e = bufA[i];
        const int c = (int)(e.y & 127u);
        bufB[celloff[c] + atomicAdd(&cellcur[c], 1)] = e;
    }
    __syncthreads();   // bufA dead; sacc live from here

    // accumulate: wave wv owns cells c = wv, wv+16, ...; lane l<40 owns
    // channels (2l, 2l+1); 8-pt unrolled, one u32 (2xbf16) load per point.
    for (int c = wv; c < TCELLS; c += 16) {
        const int s0 = celloff[c];
        const int pc = (cellcnt[c] + 7) & ~7;
        float a0 = 0.f, a1 = 0.f;
        for (int i = 0; i < pc; i += 8) {
            uint2 e[8];
#pragma unroll
            for (int r = 0; r < 8; ++r) e[r] = bufB[s0 + i + r];   // broadcast
            if (lane < 40) {
                unsigned u[8];
#pragma unroll
                for (int r = 0; r < 8; ++r)
                    u[r] = *(const unsigned*)(ctx + (e[r].y >> 7) + 2 * lane);
#pragma unroll
                for (int r = 0; r < 8; ++r) {
                    const float d  = __uint_as_float(e[r].x);
                    const float f0 = __uint_as_float(u[r] << 16);
                    const float f1 = __uint_as_float(u[r] & 0xffff0000u);
                    a0 += d * f0;
                    a1 += d * f1;
                }
            }
        }
        if (lane < 40) {
            sacc[2 * lane][c]     = a0;
            sacc[2 * lane + 1][c] = a1;
        }
    }

    // slow path for bucket overflow (~20 sigma; correctness only)
    if (total > CAP) {
        for (int blk = 0; blk < NBLK; ++blk) {
            const int dstb = segofs[blk];
            const int n    = segcnt[blk];
            if (dstb + n <= CAP) continue;
            const uint2* sp = plist + (size_t)blk * EPB + ofsmat[(size_t)blk * NBUCKET + bucket];
            const int i0 = (CAP > dstb) ? (CAP - dstb) : 0;
            for (int i = i0; i < n; ++i) {
                const uint2 e = sp[i];
                const int c = (int)(e.y & 127u);
                if ((c & 15) == wv && lane < 40) {
                    const unsigned u = *(const unsigned*)(ctx + (e.y >> 7) + 2 * lane);
                    const float dep = __uint_as_float(e.x);
                    sacc[2 * lane][c]     += dep * __uint_as_float(u << 16);
                    sacc[2 * lane + 1][c] += dep * __uint_as_float(u & 0xffff0000u);
                }
            }
        }
    }
    __syncthreads();

    // epilogue: full 64B line writes to (B,C,H,W)
    const int b  = bucket >> 7;
    const int tl = bucket & 127;
    const int tr = tl >> 3;
    const int tc = tl & 7;
    const int c0  = tid >> 4;
    const int col = tid & 15;
#pragma unroll
    for (int cc = c0; cc < CTX; cc += 64) {
#pragma unroll
        for (int r = 0; r < 8; ++r) {
            out[((size_t)(b * CTX + cc)) * BEVHW + (tr * 8 + r) * 128 + tc * 16 + col]
                = sacc[cc][r * 16 + col];
        }
    }
}

extern "C" void kernel_launch(void* const* d_in, const int* in_sizes, int n_in,
                              void* d_out, int out_size, void* d_ws, size_t ws_size,
                              hipStream_t stream)
{
    const float* img  = (const float*)d_in[0];
    const float* w    = (const float*)d_in[4];
    const float* bias = (const float*)d_in[5];
    const int*   geom = (const int*)d_in[6];
    float*       out  = (float*)d_out;

    float* ws     = (float*)d_ws;
    float* xdepth = ws + XDEPTH_OFF;
    __hip_bfloat16* ctx = (__hip_bfloat16*)(ws + CTX_OFF);
    int*   cntmat = (int*)(ws + CNTMAT_OFF);
    int*   ofsmat = (int*)(ws + OFSMAT_OFF);
    uint2* plist  = (uint2*)(ws + PLIST_OFF);

    // 1. GEMM + bias -> depth logits (fp32) / transposed context (bf16)
    {
        dim3 grid(11, 3, BNPAIR);   // 64-pixel tiles (704 = 11*64 exact)
        gemm_kernel<<<grid, 256, 0, stream>>>(img, w, bias, xdepth, ctx);
    }
    // 2. fused softmax + deterministic block-local counting sort (no atomics)
    fill_kernel<<<NBLK, 256, 0, stream>>>(xdepth, geom, plist, cntmat, ofsmat);

    // 3. fused cell-sort + gather per bucket, coalesced (B,C,H,W) writes
    gather_kernel<<<NBUCKET, 1024, 0, stream>>>(plist, cntmat, ofsmat,
                                                (const unsigned short*)ctx, out);
}